// Round 2
// baseline (338.406 us; speedup 1.0000x reference)
//
#include <hip/hip_runtime.h>
#include <hip/hip_bf16.h>

// Problem constants
#define B_ 4
#define N_ 4096
#define PD_ 1024
#define D_ 16
#define S_ 64
#define ALL_ 1024     // D*S
#define TWOALL_ 2048
#define M_ 16384      // B*N

typedef __bf16 bf16x8 __attribute__((ext_vector_type(8)));
typedef float floatx4 __attribute__((ext_vector_type(4)));

__device__ __forceinline__ unsigned short f2bf(float f) {
    unsigned int x = __float_as_uint(f);
    unsigned int r = (x + 0x7fffu + ((x >> 16) & 1u)) >> 16;
    return (unsigned short)r;
}

// ---------------- elementwise fp32 -> bf16 (n divisible by 1024) ------------
__global__ __launch_bounds__(256) void convert_f32_bf16(
    const float* __restrict__ in, unsigned short* __restrict__ out, int n4) {
    int i = blockIdx.x * 256 + threadIdx.x;
    if (i >= n4) return;
    float4 v = *(const float4*)(in + (size_t)i * 4);
    ushort4 o;
    o.x = f2bf(v.x); o.y = f2bf(v.y); o.z = f2bf(v.z); o.w = f2bf(v.w);
    *(ushort4*)(out + (size_t)i * 4) = o;
}

// ---------------- tiled transpose fp32 -> bf16 ------------------------------
// in: rows x cols (fp32, row-major) -> out: cols x rows (bf16, row-major)
__global__ void transpose_f32_bf16(const float* __restrict__ in,
                                   unsigned short* __restrict__ out,
                                   int rows, int cols) {
    __shared__ float tile[32][33];
    int bx = blockIdx.x * 32;   // col base
    int by = blockIdx.y * 32;   // row base
    int tx = threadIdx.x;       // 0..31
    int ty = threadIdx.y;       // 0..7
    #pragma unroll
    for (int i = 0; i < 32; i += 8)
        tile[ty + i][tx] = in[(size_t)(by + ty + i) * cols + bx + tx];
    __syncthreads();
    #pragma unroll
    for (int i = 0; i < 32; i += 8)
        out[(size_t)(bx + ty + i) * rows + by + tx] = f2bf(tile[tx][ty + i]);
}

// ---------------- MFMA bf16 GEMM: C(f32) = A(MxK) @ Bt(NxK)^T + bias --------
// 128x128 block tile, 4 waves (2x2), each wave 64x64 = 4x4 MFMA 16x16x32 tiles.
#define BM 128
#define BN 128
#define BK 32
#define LDK 40   // padded LDS k-stride in shorts (32 + 8 -> conflict-free)

__global__ __launch_bounds__(256) void gemm_bf16(
    const unsigned short* __restrict__ A,   // M x K row-major bf16
    const unsigned short* __restrict__ Bt,  // N x K row-major bf16
    const float* __restrict__ bias,         // N fp32
    float* __restrict__ C,                  // M x N row-major fp32
    int M, int N, int K) {

    __shared__ __align__(16) unsigned short As[BM * LDK];
    __shared__ __align__(16) unsigned short Bs[BN * LDK];

    const int tid  = threadIdx.x;
    const int lane = tid & 63;
    const int wave = tid >> 6;      // 0..3
    const int wm   = wave & 1;
    const int wn   = wave >> 1;
    const int bm0  = blockIdx.y * BM;
    const int bn0  = blockIdx.x * BN;

    floatx4 acc[4][4] = {};         // [mt][nt]

    const int lrow = lane & 15;          // row within a 16-tile
    const int kq   = (lane >> 4) * 8;    // k offset of this lane's 8 elems

    for (int k0 = 0; k0 < K; k0 += BK) {
        #pragma unroll
        for (int c = 0; c < 2; ++c) {
            int q   = tid + c * 256;
            int row = q >> 2;
            int col = (q & 3) * 8;
            uint4 va = *(const uint4*)(A  + (size_t)(bm0 + row) * K + k0 + col);
            *(uint4*)(As + row * LDK + col) = va;
            uint4 vb = *(const uint4*)(Bt + (size_t)(bn0 + row) * K + k0 + col);
            *(uint4*)(Bs + row * LDK + col) = vb;
        }
        __syncthreads();

        bf16x8 af[4], bfr[4];
        #pragma unroll
        for (int mt = 0; mt < 4; ++mt) {
            int r = wm * 64 + mt * 16 + lrow;
            af[mt] = *(const bf16x8*)(As + r * LDK + kq);
        }
        #pragma unroll
        for (int nt = 0; nt < 4; ++nt) {
            int r = wn * 64 + nt * 16 + lrow;
            bfr[nt] = *(const bf16x8*)(Bs + r * LDK + kq);
        }
        #pragma unroll
        for (int mt = 0; mt < 4; ++mt)
            #pragma unroll
            for (int nt = 0; nt < 4; ++nt)
                acc[mt][nt] = __builtin_amdgcn_mfma_f32_16x16x32_bf16(
                    af[mt], bfr[nt], acc[mt][nt], 0, 0, 0);
        __syncthreads();
    }

    // C/D layout (m89-verified): col = lane&15, row = (lane>>4)*4 + r
    #pragma unroll
    for (int nt = 0; nt < 4; ++nt) {
        int col = bn0 + wn * 64 + nt * 16 + (lane & 15);
        float bv = bias[col];
        #pragma unroll
        for (int mt = 0; mt < 4; ++mt) {
            #pragma unroll
            for (int r = 0; r < 4; ++r) {
                int row = bm0 + wm * 64 + mt * 16 + (lane >> 4) * 4 + r;
                C[(size_t)row * N + col] = acc[mt][nt][r] + bv;
            }
        }
    }
}

// ---------------- middle: softmax + banded accumulation ----------------------
// P layout: [b][n][2][D][S] fp32. Output A2: [b][n][d*S + s] bf16.
// Qg[b,n,d,s] = sum_{i=0}^{d-1} softmax_j(L[b,n,j,s])[i] * R[b,n+i, d-1-i, s]
// with R[b,m] = P[b,(m+1)%N,1]; zeroed when chunk==last && t+d>=D (Q1 mask).
__global__ __launch_bounds__(256) void middle_kernel(
    const float* __restrict__ P,
    unsigned short* __restrict__ A2) {

    int idx = blockIdx.x * 256 + threadIdx.x;
    int s   = idx & 63;
    int r   = idx >> 6;            // b*N + n
    int n   = r & (N_ - 1);
    const int t = n & (D_ - 1);
    const int c = n >> 4;

    // softmax over the 16 L values (fp32)
    const float* Lp = P + (size_t)r * TWOALL_ + s;   // c2=0, d=0
    float w[16];
    float mx = -1e30f;
    #pragma unroll
    for (int j = 0; j < 16; ++j) {
        w[j] = Lp[j * S_];
        mx = fmaxf(mx, w[j]);
    }
    float sum = 0.f;
    #pragma unroll
    for (int j = 0; j < 16; ++j) {
        w[j] = __expf(w[j] - mx);
        sum += w[j];
    }
    float inv = 1.0f / sum;

    float q[16];
    #pragma unroll
    for (int d = 0; d < 16; ++d) q[d] = 0.f;

    // q[i+k+1] += w[i] * R[n+i][k],  i+k <= 14
    #pragma unroll
    for (int i = 0; i < 15; ++i) {
        int np = n + i + 1;
        if (np >= N_) np -= N_;
        int b = r >> 12;
        const float* Rp = P + (((size_t)(b * N_ + np)) * 2 + 1) * ALL_ + s;
        #pragma unroll
        for (int k = 0; k < 15 - i; ++k) {
            q[i + k + 1] += w[i] * Rp[k * S_];
        }
    }

    unsigned short* out = A2 + (size_t)r * ALL_ + s;
    bool last = (c == (N_ / D_) - 1);
    #pragma unroll
    for (int d = 0; d < 16; ++d) {
        float v = (d == 0) ? 0.f : q[d] * inv;
        if (last && (t + d >= D_)) v = 0.f;
        out[d * S_] = f2bf(v);
    }
}

// ---------------- launch -----------------------------------------------------
extern "C" void kernel_launch(void* const* d_in, const int* in_sizes, int n_in,
                              void* d_out, int out_size, void* d_ws, size_t ws_size,
                              hipStream_t stream) {
    const float* x   = (const float*)d_in[0]; // (4,4096,1024) fp32
    const float* W_r = (const float*)d_in[1]; // (1024,2048)   fp32
    const float* b_r = (const float*)d_in[2]; // (2048,)       fp32
    const float* W_w = (const float*)d_in[3]; // (1024,1024)   fp32
    const float* b_w = (const float*)d_in[4]; // (1024,)       fp32
    float* out = (float*)d_out;               // (4,4096,1024) fp32

    // workspace layout (bytes):
    //   P    fp32  16384*2048*4 = 134.2 MB
    //   xbf  bf16  16384*1024*2 =  33.6 MB
    //   A2   bf16  16384*1024*2 =  33.6 MB
    //   WrT  bf16   2048*1024*2 =   4.2 MB
    //   WwT  bf16   1024*1024*2 =   2.1 MB   total ~207.6 MB
    char* ws = (char*)d_ws;
    float*          P   = (float*)ws;
    unsigned short* xbf = (unsigned short*)(ws + (size_t)M_ * TWOALL_ * 4);
    unsigned short* A2  = xbf + (size_t)M_ * ALL_;
    unsigned short* WrT = A2  + (size_t)M_ * ALL_;
    unsigned short* WwT = WrT + (size_t)TWOALL_ * PD_;

    // convert x to bf16: 16777216 elems / 4 = 4194304 threads
    convert_f32_bf16<<<dim3((M_ * PD_ / 4 + 255) / 256), 256, 0, stream>>>(
        x, xbf, M_ * PD_ / 4);

    dim3 tb(32, 8);
    transpose_f32_bf16<<<dim3(TWOALL_ / 32, PD_ / 32), tb, 0, stream>>>(W_r, WrT, PD_, TWOALL_);
    transpose_f32_bf16<<<dim3(ALL_ / 32, PD_ / 32), tb, 0, stream>>>(W_w, WwT, PD_, ALL_);

    // GEMM1: P = x @ W_r + b_r   (M=16384, N=2048, K=1024), fp32 out
    gemm_bf16<<<dim3(TWOALL_ / BN, M_ / BM), 256, 0, stream>>>(
        xbf, WrT, b_r, P, M_, TWOALL_, PD_);

    // middle: 4*4096*64 threads
    middle_kernel<<<dim3((B_ * N_ * S_) / 256), 256, 0, stream>>>(P, A2);

    // GEMM2: out = A2 @ W_w + b_w   (M=16384, N=1024, K=1024), fp32 out
    gemm_bf16<<<dim3(ALL_ / BN, M_ / BM), 256, 0, stream>>>(
        A2, WwT, b_w, out, M_, ALL_, PD_);
}

// Round 3
// 332.362 us; speedup vs baseline: 1.0182x; 1.0182x over previous
//
#include <hip/hip_runtime.h>
#include <hip/hip_bf16.h>

// Problem constants
#define B_ 4
#define N_ 4096
#define PD_ 1024
#define D_ 16
#define S_ 64
#define ALL_ 1024     // D*S
#define TWOALL_ 2048
#define M_ 16384      // B*N

typedef __bf16 bf16x8 __attribute__((ext_vector_type(8)));
typedef float floatx4 __attribute__((ext_vector_type(4)));

__device__ __forceinline__ unsigned short f2bf(float f) {
    unsigned int x = __float_as_uint(f);
    unsigned int r = (x + 0x7fffu + ((x >> 16) & 1u)) >> 16;
    return (unsigned short)r;
}

// async global->LDS DMA, 16 B per lane; LDS dest = base + lane*16 (HW rule)
__device__ __forceinline__ void load_lds_16(const void* g, void* l) {
    __builtin_amdgcn_global_load_lds(
        (const __attribute__((address_space(1))) void*)g,
        (__attribute__((address_space(3))) void*)l, 16, 0, 0);
}

// ---------------- elementwise fp32 -> bf16 ----------------------------------
__global__ __launch_bounds__(256) void convert_f32_bf16(
    const float* __restrict__ in, unsigned short* __restrict__ out, int n4) {
    int i = blockIdx.x * 256 + threadIdx.x;
    if (i >= n4) return;
    float4 v = *(const float4*)(in + (size_t)i * 4);
    ushort4 o;
    o.x = f2bf(v.x); o.y = f2bf(v.y); o.z = f2bf(v.z); o.w = f2bf(v.w);
    *(ushort4*)(out + (size_t)i * 4) = o;
}

// ---------------- tiled transpose fp32 -> bf16 ------------------------------
__global__ void transpose_f32_bf16(const float* __restrict__ in,
                                   unsigned short* __restrict__ out,
                                   int rows, int cols) {
    __shared__ float tile[32][33];
    int bx = blockIdx.x * 32;
    int by = blockIdx.y * 32;
    int tx = threadIdx.x;
    int ty = threadIdx.y;
    #pragma unroll
    for (int i = 0; i < 32; i += 8)
        tile[ty + i][tx] = in[(size_t)(by + ty + i) * cols + bx + tx];
    __syncthreads();
    #pragma unroll
    for (int i = 0; i < 32; i += 8)
        out[(size_t)(bx + ty + i) * rows + by + tx] = f2bf(tile[tx][ty + i]);
}

// ---------------- MFMA bf16 GEMM: C(f32) = A(MxK) @ Bt(NxK)^T + bias --------
// m97 structure: 128x128 tile, BK=32, 4 waves 2x2, global_load_lds width=16,
// UNPADDED LDS (required by global_load_lds lane-contiguous dest rule).
#define BM 128
#define BN 128
#define BK 32

__global__ __launch_bounds__(256) void gemm_bf16(
    const unsigned short* __restrict__ A,   // M x K row-major bf16
    const unsigned short* __restrict__ Bt,  // N x K row-major bf16
    const float* __restrict__ bias,         // N fp32
    float* __restrict__ C,                  // M x N row-major fp32
    int M, int N, int K) {

    __shared__ __align__(16) unsigned short As[BM * BK];  // 8 KB
    __shared__ __align__(16) unsigned short Bs[BN * BK];  // 8 KB

    const int tid  = threadIdx.x;
    const int lane = tid & 63;
    const int wave = tid >> 6;      // 0..3
    const int wm   = wave & 1;
    const int wn   = wave >> 1;
    const int bm0  = blockIdx.y * BM;
    const int bn0  = blockIdx.x * BN;

    floatx4 acc[4][4] = {};

    const int lrow = lane & 15;          // row within a 16-tile
    const int kq   = (lane >> 4) * 8;    // k offset of this lane's 8 elems

    // staging lane map: within a 1024B chunk (16 rows x 64B),
    // lane i -> row i>>2, col (i&3)*8 elems  (byte off = 16*i, matches HW)
    const int ar = lane >> 2;
    const int ac = (lane & 3) * 8;

    for (int k0 = 0; k0 < K; k0 += BK) {
        #pragma unroll
        for (int c = 0; c < 2; ++c) {
            int chunk = wave * 2 + c;            // 0..7
            int row   = chunk * 16 + ar;
            load_lds_16(A  + (size_t)(bm0 + row) * K + k0 + ac, As + chunk * 512);
            load_lds_16(Bt + (size_t)(bn0 + row) * K + k0 + ac, Bs + chunk * 512);
        }
        __syncthreads();   // compiler emits vmcnt(0) drain before barrier

        bf16x8 af[4], bfr[4];
        #pragma unroll
        for (int mt = 0; mt < 4; ++mt) {
            int r = wm * 64 + mt * 16 + lrow;
            af[mt] = *(const bf16x8*)(As + r * BK + kq);
        }
        #pragma unroll
        for (int nt = 0; nt < 4; ++nt) {
            int r = wn * 64 + nt * 16 + lrow;
            bfr[nt] = *(const bf16x8*)(Bs + r * BK + kq);
        }
        #pragma unroll
        for (int mt = 0; mt < 4; ++mt)
            #pragma unroll
            for (int nt = 0; nt < 4; ++nt)
                acc[mt][nt] = __builtin_amdgcn_mfma_f32_16x16x32_bf16(
                    af[mt], bfr[nt], acc[mt][nt], 0, 0, 0);
        __syncthreads();
    }

    // C/D layout (m89-verified): col = lane&15, row = (lane>>4)*4 + r
    #pragma unroll
    for (int nt = 0; nt < 4; ++nt) {
        int col = bn0 + wn * 64 + nt * 16 + (lane & 15);
        float bv = bias[col];
        #pragma unroll
        for (int mt = 0; mt < 4; ++mt) {
            #pragma unroll
            for (int r = 0; r < 4; ++r) {
                int row = bm0 + wm * 64 + mt * 16 + (lane >> 4) * 4 + r;
                C[(size_t)row * N + col] = acc[mt][nt][r] + bv;
            }
        }
    }
}

// ---------------- middle: softmax + banded accumulation ----------------------
__global__ __launch_bounds__(256) void middle_kernel(
    const float* __restrict__ P,
    unsigned short* __restrict__ A2) {

    int idx = blockIdx.x * 256 + threadIdx.x;
    int s   = idx & 63;
    int r   = idx >> 6;            // b*N + n
    int n   = r & (N_ - 1);
    const int t = n & (D_ - 1);
    const int c = n >> 4;

    const float* Lp = P + (size_t)r * TWOALL_ + s;
    float w[16];
    float mx = -1e30f;
    #pragma unroll
    for (int j = 0; j < 16; ++j) {
        w[j] = Lp[j * S_];
        mx = fmaxf(mx, w[j]);
    }
    float sum = 0.f;
    #pragma unroll
    for (int j = 0; j < 16; ++j) {
        w[j] = __expf(w[j] - mx);
        sum += w[j];
    }
    float inv = 1.0f / sum;

    float q[16];
    #pragma unroll
    for (int d = 0; d < 16; ++d) q[d] = 0.f;

    #pragma unroll
    for (int i = 0; i < 15; ++i) {
        int np = n + i + 1;
        if (np >= N_) np -= N_;
        int b = r >> 12;
        const float* Rp = P + (((size_t)(b * N_ + np)) * 2 + 1) * ALL_ + s;
        #pragma unroll
        for (int k = 0; k < 15 - i; ++k) {
            q[i + k + 1] += w[i] * Rp[k * S_];
        }
    }

    unsigned short* out = A2 + (size_t)r * ALL_ + s;
    bool last = (c == (N_ / D_) - 1);
    #pragma unroll
    for (int d = 0; d < 16; ++d) {
        float v = (d == 0) ? 0.f : q[d] * inv;
        if (last && (t + d >= D_)) v = 0.f;
        out[d * S_] = f2bf(v);
    }
}

// ---------------- launch -----------------------------------------------------
extern "C" void kernel_launch(void* const* d_in, const int* in_sizes, int n_in,
                              void* d_out, int out_size, void* d_ws, size_t ws_size,
                              hipStream_t stream) {
    const float* x   = (const float*)d_in[0];
    const float* W_r = (const float*)d_in[1];
    const float* b_r = (const float*)d_in[2];
    const float* W_w = (const float*)d_in[3];
    const float* b_w = (const float*)d_in[4];
    float* out = (float*)d_out;

    char* ws = (char*)d_ws;
    float*          P   = (float*)ws;                                   // 134.2 MB
    unsigned short* xbf = (unsigned short*)(ws + (size_t)M_ * TWOALL_ * 4);
    unsigned short* A2  = xbf + (size_t)M_ * ALL_;
    unsigned short* WrT = A2  + (size_t)M_ * ALL_;
    unsigned short* WwT = WrT + (size_t)TWOALL_ * PD_;

    convert_f32_bf16<<<dim3((M_ * PD_ / 4 + 255) / 256), 256, 0, stream>>>(
        x, xbf, M_ * PD_ / 4);

    dim3 tb(32, 8);
    transpose_f32_bf16<<<dim3(TWOALL_ / 32, PD_ / 32), tb, 0, stream>>>(W_r, WrT, PD_, TWOALL_);
    transpose_f32_bf16<<<dim3(ALL_ / 32, PD_ / 32), tb, 0, stream>>>(W_w, WwT, PD_, ALL_);

    // GEMM1: P = x @ W_r + b_r   (M=16384, N=2048, K=1024)
    gemm_bf16<<<dim3(TWOALL_ / BN, M_ / BM), 256, 0, stream>>>(
        xbf, WrT, b_r, P, M_, TWOALL_, PD_);

    middle_kernel<<<dim3((B_ * N_ * S_) / 256), 256, 0, stream>>>(P, A2);

    // GEMM2: out = A2 @ W_w + b_w   (M=16384, N=1024, K=1024)
    gemm_bf16<<<dim3(ALL_ / BN, M_ / BM), 256, 0, stream>>>(
        A2, WwT, b_w, out, M_, ALL_, PD_);
}

// Round 4
// 290.304 us; speedup vs baseline: 1.1657x; 1.1449x over previous
//
#include <hip/hip_runtime.h>
#include <hip/hip_bf16.h>

// Problem constants
#define B_ 4
#define N_ 4096
#define PD_ 1024
#define D_ 16
#define S_ 64
#define ALL_ 1024     // D*S
#define TWOALL_ 2048
#define M_ 16384      // B*N

typedef __bf16 bf16x8 __attribute__((ext_vector_type(8)));
typedef float floatx4 __attribute__((ext_vector_type(4)));

__device__ __forceinline__ float bf2f(unsigned short u) {
    union { unsigned int i; float f; } v;
    v.i = ((unsigned int)u) << 16;
    return v.f;
}

__device__ __forceinline__ unsigned short f2bf(float f) {
    unsigned int x = __float_as_uint(f);
    unsigned int r = (x + 0x7fffu + ((x >> 16) & 1u)) >> 16;
    return (unsigned short)r;
}

// async global->LDS DMA, 16 B per lane; LDS dest = wave-uniform base + lane*16
__device__ __forceinline__ void load_lds_16(const void* g, void* l) {
    __builtin_amdgcn_global_load_lds(
        (const __attribute__((address_space(1))) void*)g,
        (__attribute__((address_space(3))) void*)l, 16, 0, 0);
}

// ---------------- elementwise fp32 -> bf16 ----------------------------------
__global__ __launch_bounds__(256) void convert_f32_bf16(
    const float* __restrict__ in, unsigned short* __restrict__ out, int n4) {
    int i = blockIdx.x * 256 + threadIdx.x;
    if (i >= n4) return;
    float4 v = *(const float4*)(in + (size_t)i * 4);
    ushort4 o;
    o.x = f2bf(v.x); o.y = f2bf(v.y); o.z = f2bf(v.z); o.w = f2bf(v.w);
    *(ushort4*)(out + (size_t)i * 4) = o;
}

// ---------------- tiled transpose fp32 -> bf16 ------------------------------
__global__ void transpose_f32_bf16(const float* __restrict__ in,
                                   unsigned short* __restrict__ out,
                                   int rows, int cols) {
    __shared__ float tile[32][33];
    int bx = blockIdx.x * 32;
    int by = blockIdx.y * 32;
    int tx = threadIdx.x;
    int ty = threadIdx.y;
    #pragma unroll
    for (int i = 0; i < 32; i += 8)
        tile[ty + i][tx] = in[(size_t)(by + ty + i) * cols + bx + tx];
    __syncthreads();
    #pragma unroll
    for (int i = 0; i < 32; i += 8)
        out[(size_t)(bx + ty + i) * rows + by + tx] = f2bf(tile[tx][ty + i]);
}

// ---------------- MFMA bf16 GEMM -------------------------------------------
// 128x128 tile, BK=64 (one barrier pair per 64 K), 4 waves 2x2,
// global_load_lds width=16 staging, XOR-swizzled LDS (conflict-free b128),
// XCD-aware block swizzle (y-row's column blocks co-resident on one XCD).
// C output: bf16 (OUT_BF=1) or fp32 (OUT_BF=0).
#define BM 128
#define BN 128
#define BK 64

template <int OUT_BF>
__global__ __launch_bounds__(256) void gemm_bf16(
    const unsigned short* __restrict__ A,   // M x K row-major bf16
    const unsigned short* __restrict__ Bt,  // N x K row-major bf16
    const float* __restrict__ bias,         // N fp32
    void* __restrict__ Cv,                  // M x N row-major
    int M, int N, int K, int gxl) {         // gxl = log2(grid cols)

    __shared__ __align__(16) unsigned short As[BM * BK];  // 16 KB
    __shared__ __align__(16) unsigned short Bs[BN * BK];  // 16 KB

    const int tid  = threadIdx.x;
    const int lane = tid & 63;
    const int wave = tid >> 6;      // 0..3
    const int wm   = wave & 1;
    const int wn   = wave >> 1;

    // XCD swizzle: flat -> (bx, by) s.t. one y-row's blocks share an XCD
    const int flat = blockIdx.x;
    const int xcd  = flat & 7;
    const int slot = flat >> 3;
    const int bx   = slot & ((1 << gxl) - 1);
    const int by   = xcd * 16 + (slot >> gxl);   // gy/8 == 16 for both GEMMs
    const int bm0  = by * BM;
    const int bn0  = bx * BN;

    floatx4 acc[4][4] = {};

    const int lrow = lane & 15;

    // staging lane map within an 8-row x 64-col chunk (1024 B):
    // lane i -> row i>>3, xor-swizzled group: fetch global group (i&7)^(i>>3)
    const int srow = lane >> 3;
    const int sg   = (lane & 7) ^ srow;

    for (int k0 = 0; k0 < K; k0 += BK) {
        #pragma unroll
        for (int c = 0; c < 4; ++c) {
            int chunk = wave * 4 + c;            // 0..15
            int row   = chunk * 8 + srow;
            load_lds_16(A  + (size_t)(bm0 + row) * K + k0 + sg * 8, As + chunk * 512);
            load_lds_16(Bt + (size_t)(bn0 + row) * K + k0 + sg * 8, Bs + chunk * 512);
        }
        __syncthreads();

        #pragma unroll
        for (int kk = 0; kk < 2; ++kk) {
            const int G = (lane >> 4) + kk * 4;   // global k-group 0..7
            bf16x8 af[4], bfr[4];
            #pragma unroll
            for (int mt = 0; mt < 4; ++mt) {
                int r = wm * 64 + mt * 16 + lrow;
                af[mt] = *(const bf16x8*)(As + r * BK + ((G ^ (r & 7)) * 8));
            }
            #pragma unroll
            for (int nt = 0; nt < 4; ++nt) {
                int r = wn * 64 + nt * 16 + lrow;
                bfr[nt] = *(const bf16x8*)(Bs + r * BK + ((G ^ (r & 7)) * 8));
            }
            #pragma unroll
            for (int mt = 0; mt < 4; ++mt)
                #pragma unroll
                for (int nt = 0; nt < 4; ++nt)
                    acc[mt][nt] = __builtin_amdgcn_mfma_f32_16x16x32_bf16(
                        af[mt], bfr[nt], acc[mt][nt], 0, 0, 0);
        }
        __syncthreads();
    }

    // C/D layout (m89-verified): col = lane&15, row = (lane>>4)*4 + r
    #pragma unroll
    for (int nt = 0; nt < 4; ++nt) {
        int col = bn0 + wn * 64 + nt * 16 + (lane & 15);
        float bv = bias[col];
        #pragma unroll
        for (int mt = 0; mt < 4; ++mt) {
            #pragma unroll
            for (int r = 0; r < 4; ++r) {
                int row = bm0 + wm * 64 + mt * 16 + (lane >> 4) * 4 + r;
                float v = acc[mt][nt][r] + bv;
                if (OUT_BF)
                    ((unsigned short*)Cv)[(size_t)row * N + col] = f2bf(v);
                else
                    ((float*)Cv)[(size_t)row * N + col] = v;
            }
        }
    }
}

// ---------------- middle: softmax + banded accumulation (bf16 P) ------------
// P: [b][n][2][D][S] bf16. A2: [b][n][d*S+s] bf16.
// Qg[b,n,d,s] = sum_{i<d} softmax_j(L[b,n,j,s])[i] * R[b,n+i, d-1-i, s],
// R[b,m] = P[b,(m+1)%N,1]; zeroed when chunk==last && t+d>=D.
__global__ __launch_bounds__(256) void middle_kernel(
    const unsigned short* __restrict__ P,
    unsigned short* __restrict__ A2) {

    int idx = blockIdx.x * 256 + threadIdx.x;
    int s   = idx & 63;
    int r   = idx >> 6;            // b*N + n
    int n   = r & (N_ - 1);
    const int t = n & (D_ - 1);
    const int c = n >> 4;

    const unsigned short* Lp = P + (size_t)r * TWOALL_ + s;
    float w[16];
    float mx = -1e30f;
    #pragma unroll
    for (int j = 0; j < 16; ++j) {
        w[j] = bf2f(Lp[j * S_]);
        mx = fmaxf(mx, w[j]);
    }
    float sum = 0.f;
    #pragma unroll
    for (int j = 0; j < 16; ++j) {
        w[j] = __expf(w[j] - mx);
        sum += w[j];
    }
    float inv = 1.0f / sum;

    float q[16];
    #pragma unroll
    for (int d = 0; d < 16; ++d) q[d] = 0.f;

    #pragma unroll
    for (int i = 0; i < 15; ++i) {
        int np = n + i + 1;
        if (np >= N_) np -= N_;
        int b = r >> 12;
        const unsigned short* Rp = P + (((size_t)(b * N_ + np)) * 2 + 1) * ALL_ + s;
        #pragma unroll
        for (int k = 0; k < 15 - i; ++k) {
            q[i + k + 1] += w[i] * bf2f(Rp[k * S_]);
        }
    }

    unsigned short* out = A2 + (size_t)r * ALL_ + s;
    bool last = (c == (N_ / D_) - 1);
    #pragma unroll
    for (int d = 0; d < 16; ++d) {
        float v = (d == 0) ? 0.f : q[d] * inv;
        if (last && (t + d >= D_)) v = 0.f;
        out[d * S_] = f2bf(v);
    }
}

// ---------------- launch -----------------------------------------------------
extern "C" void kernel_launch(void* const* d_in, const int* in_sizes, int n_in,
                              void* d_out, int out_size, void* d_ws, size_t ws_size,
                              hipStream_t stream) {
    const float* x   = (const float*)d_in[0];
    const float* W_r = (const float*)d_in[1];
    const float* b_r = (const float*)d_in[2];
    const float* W_w = (const float*)d_in[3];
    const float* b_w = (const float*)d_in[4];
    float* out = (float*)d_out;

    // workspace: P bf16 67.1MB | xbf 33.6MB | A2 33.6MB | WrT 4.2MB | WwT 2.1MB
    unsigned short* ws  = (unsigned short*)d_ws;
    unsigned short* P   = ws;
    unsigned short* xbf = P   + (size_t)M_ * TWOALL_;
    unsigned short* A2  = xbf + (size_t)M_ * ALL_;
    unsigned short* WrT = A2  + (size_t)M_ * ALL_;
    unsigned short* WwT = WrT + (size_t)TWOALL_ * PD_;

    convert_f32_bf16<<<dim3((M_ * PD_ / 4 + 255) / 256), 256, 0, stream>>>(
        x, xbf, M_ * PD_ / 4);

    dim3 tb(32, 8);
    transpose_f32_bf16<<<dim3(TWOALL_ / 32, PD_ / 32), tb, 0, stream>>>(W_r, WrT, PD_, TWOALL_);
    transpose_f32_bf16<<<dim3(ALL_ / 32, PD_ / 32), tb, 0, stream>>>(W_w, WwT, PD_, ALL_);

    // GEMM1: P(bf16) = x @ W_r + b_r   (M=16384, N=2048, K=1024), grid 16x128
    gemm_bf16<1><<<dim3((TWOALL_ / BN) * (M_ / BM)), 256, 0, stream>>>(
        xbf, WrT, b_r, P, M_, TWOALL_, PD_, 4);

    middle_kernel<<<dim3((B_ * N_ * S_) / 256), 256, 0, stream>>>(P, A2);

    // GEMM2: out(f32) = A2 @ W_w + b_w  (M=16384, N=1024, K=1024), grid 8x128
    gemm_bf16<0><<<dim3((ALL_ / BN) * (M_ / BM)), 256, 0, stream>>>(
        A2, WwT, b_w, out, M_, ALL_, PD_, 3);
}

// Round 5
// 265.252 us; speedup vs baseline: 1.2758x; 1.0944x over previous
//
#include <hip/hip_runtime.h>
#include <hip/hip_bf16.h>

// Problem constants
#define B_ 4
#define N_ 4096
#define PD_ 1024
#define D_ 16
#define S_ 64
#define ALL_ 1024     // D*S
#define TWOALL_ 2048
#define M_ 16384      // B*N

typedef __bf16 bf16x8 __attribute__((ext_vector_type(8)));
typedef float floatx4 __attribute__((ext_vector_type(4)));

__device__ __forceinline__ float bf2f(unsigned short u) {
    union { unsigned int i; float f; } v;
    v.i = ((unsigned int)u) << 16;
    return v.f;
}

__device__ __forceinline__ unsigned short f2bf(float f) {
    unsigned int x = __float_as_uint(f);
    unsigned int r = (x + 0x7fffu + ((x >> 16) & 1u)) >> 16;
    return (unsigned short)r;
}

// async global->LDS DMA, 16 B per lane; LDS dest = wave-uniform base + lane*16
__device__ __forceinline__ void load_lds_16(const void* g, void* l) {
    __builtin_amdgcn_global_load_lds(
        (const __attribute__((address_space(1))) void*)g,
        (__attribute__((address_space(3))) void*)l, 16, 0, 0);
}

// ---------------- elementwise fp32 -> bf16 ----------------------------------
__global__ __launch_bounds__(256) void convert_f32_bf16(
    const float* __restrict__ in, unsigned short* __restrict__ out, int n4) {
    int i = blockIdx.x * 256 + threadIdx.x;
    if (i >= n4) return;
    float4 v = *(const float4*)(in + (size_t)i * 4);
    ushort4 o;
    o.x = f2bf(v.x); o.y = f2bf(v.y); o.z = f2bf(v.z); o.w = f2bf(v.w);
    *(ushort4*)(out + (size_t)i * 4) = o;
}

// ---------------- tiled transpose fp32 -> bf16 ------------------------------
__global__ void transpose_f32_bf16(const float* __restrict__ in,
                                   unsigned short* __restrict__ out,
                                   int rows, int cols) {
    __shared__ float tile[32][33];
    int bx = blockIdx.x * 32;
    int by = blockIdx.y * 32;
    int tx = threadIdx.x;
    int ty = threadIdx.y;
    #pragma unroll
    for (int i = 0; i < 32; i += 8)
        tile[ty + i][tx] = in[(size_t)(by + ty + i) * cols + bx + tx];
    __syncthreads();
    #pragma unroll
    for (int i = 0; i < 32; i += 8)
        out[(size_t)(bx + ty + i) * rows + by + tx] = f2bf(tile[tx][ty + i]);
}

// ---------------- MFMA bf16 GEMM -------------------------------------------
// LDS-read-pipe-optimized: BM=128 x BN=256 tile, 4 waves (2 in M x 2 in N),
// wave tile 64x128 (acc 4x8 = 128 fp32/lane). Fragment reads per MFMA:
// 12 ds_read_b128 : 32 MFMA per k32 (vs 8:16 for 64x64) -> LDS pipe no longer
// the limiter. global_load_lds width=16 staging, XOR-swizzled LDS layout,
// XCD-aware block swizzle.
#define BM 128
#define BN 256
#define BK 64

template <int OUT_BF>
__global__ __launch_bounds__(256, 2) void gemm_bf16(
    const unsigned short* __restrict__ A,   // M x K row-major bf16
    const unsigned short* __restrict__ Bt,  // N x K row-major bf16
    const float* __restrict__ bias,         // N fp32
    void* __restrict__ Cv,                  // M x N row-major
    int M, int N, int K, int gxl) {         // gxl = log2(grid cols)

    __shared__ __align__(16) unsigned short As[BM * BK];  // 16 KB
    __shared__ __align__(16) unsigned short Bs[BN * BK];  // 32 KB

    const int tid  = threadIdx.x;
    const int lane = tid & 63;
    const int wave = tid >> 6;      // 0..3
    const int wm   = wave & 1;      // 2 waves down (64 rows each)
    const int wn   = wave >> 1;     // 2 waves across (128 cols each)

    // XCD swizzle: one y-row's column blocks co-resident on one XCD
    const int flat = blockIdx.x;
    const int xcd  = flat & 7;
    const int slot = flat >> 3;
    const int bx   = slot & ((1 << gxl) - 1);
    const int by   = xcd * 16 + (slot >> gxl);   // grid-y/8 == 16 here
    const int bm0  = by * BM;
    const int bn0  = bx * BN;

    floatx4 acc[4][8] = {};          // 128 fp32 accumulator regs

    const int lrow = lane & 15;

    // staging lane map within an 8-row x 64-col chunk (1024 B):
    // lane i -> row i>>3, xor-swizzled col group (i&7)^(i>>3)
    const int srow = lane >> 3;
    const int sg   = (lane & 7) ^ srow;

    for (int k0 = 0; k0 < K; k0 += BK) {
        // stage A (16 chunks) + B (32 chunks); 4 + 8 chunks per wave
        #pragma unroll
        for (int c = 0; c < 4; ++c) {
            int chunk = wave * 4 + c;            // 0..15
            int row   = chunk * 8 + srow;
            load_lds_16(A + (size_t)(bm0 + row) * K + k0 + sg * 8, As + chunk * 512);
        }
        #pragma unroll
        for (int c = 0; c < 8; ++c) {
            int chunk = wave * 8 + c;            // 0..31
            int row   = chunk * 8 + srow;
            load_lds_16(Bt + (size_t)(bn0 + row) * K + k0 + sg * 8, Bs + chunk * 512);
        }
        __syncthreads();

        #pragma unroll
        for (int kk = 0; kk < 2; ++kk) {
            const int G = (lane >> 4) + kk * 4;   // k-group 0..7
            bf16x8 af[4], bfr[8];
            #pragma unroll
            for (int mt = 0; mt < 4; ++mt) {
                int r = wm * 64 + mt * 16 + lrow;
                af[mt] = *(const bf16x8*)(As + r * BK + ((G ^ (r & 7)) * 8));
            }
            #pragma unroll
            for (int nt = 0; nt < 8; ++nt) {
                int r = wn * 128 + nt * 16 + lrow;
                bfr[nt] = *(const bf16x8*)(Bs + r * BK + ((G ^ (r & 7)) * 8));
            }
            #pragma unroll
            for (int mt = 0; mt < 4; ++mt)
                #pragma unroll
                for (int nt = 0; nt < 8; ++nt)
                    acc[mt][nt] = __builtin_amdgcn_mfma_f32_16x16x32_bf16(
                        af[mt], bfr[nt], acc[mt][nt], 0, 0, 0);
        }
        __syncthreads();
    }

    // C/D layout (m89-verified): col = lane&15, row = (lane>>4)*4 + r
    #pragma unroll
    for (int nt = 0; nt < 8; ++nt) {
        int col = bn0 + wn * 128 + nt * 16 + (lane & 15);
        float bv = bias[col];
        #pragma unroll
        for (int mt = 0; mt < 4; ++mt) {
            #pragma unroll
            for (int r = 0; r < 4; ++r) {
                int row = bm0 + wm * 64 + mt * 16 + (lane >> 4) * 4 + r;
                float v = acc[mt][nt][r] + bv;
                if (OUT_BF)
                    ((unsigned short*)Cv)[(size_t)row * N + col] = f2bf(v);
                else
                    ((float*)Cv)[(size_t)row * N + col] = v;
            }
        }
    }
}

// ---------------- middle: softmax + banded accumulation (bf16 P) ------------
__global__ __launch_bounds__(256) void middle_kernel(
    const unsigned short* __restrict__ P,
    unsigned short* __restrict__ A2) {

    int idx = blockIdx.x * 256 + threadIdx.x;
    int s   = idx & 63;
    int r   = idx >> 6;            // b*N + n
    int n   = r & (N_ - 1);
    const int t = n & (D_ - 1);
    const int c = n >> 4;

    const unsigned short* Lp = P + (size_t)r * TWOALL_ + s;
    float w[16];
    float mx = -1e30f;
    #pragma unroll
    for (int j = 0; j < 16; ++j) {
        w[j] = bf2f(Lp[j * S_]);
        mx = fmaxf(mx, w[j]);
    }
    float sum = 0.f;
    #pragma unroll
    for (int j = 0; j < 16; ++j) {
        w[j] = __expf(w[j] - mx);
        sum += w[j];
    }
    float inv = 1.0f / sum;

    float q[16];
    #pragma unroll
    for (int d = 0; d < 16; ++d) q[d] = 0.f;

    #pragma unroll
    for (int i = 0; i < 15; ++i) {
        int np = n + i + 1;
        if (np >= N_) np -= N_;
        int b = r >> 12;
        const unsigned short* Rp = P + (((size_t)(b * N_ + np)) * 2 + 1) * ALL_ + s;
        #pragma unroll
        for (int k = 0; k < 15 - i; ++k) {
            q[i + k + 1] += w[i] * bf2f(Rp[k * S_]);
        }
    }

    unsigned short* out = A2 + (size_t)r * ALL_ + s;
    bool last = (c == (N_ / D_) - 1);
    #pragma unroll
    for (int d = 0; d < 16; ++d) {
        float v = (d == 0) ? 0.f : q[d] * inv;
        if (last && (t + d >= D_)) v = 0.f;
        out[d * S_] = f2bf(v);
    }
}

// ---------------- launch -----------------------------------------------------
extern "C" void kernel_launch(void* const* d_in, const int* in_sizes, int n_in,
                              void* d_out, int out_size, void* d_ws, size_t ws_size,
                              hipStream_t stream) {
    const float* x   = (const float*)d_in[0];
    const float* W_r = (const float*)d_in[1];
    const float* b_r = (const float*)d_in[2];
    const float* W_w = (const float*)d_in[3];
    const float* b_w = (const float*)d_in[4];
    float* out = (float*)d_out;

    // workspace: P bf16 67.1MB | xbf 33.6MB | A2 33.6MB | WrT 4.2MB | WwT 2.1MB
    unsigned short* ws  = (unsigned short*)d_ws;
    unsigned short* P   = ws;
    unsigned short* xbf = P   + (size_t)M_ * TWOALL_;
    unsigned short* A2  = xbf + (size_t)M_ * ALL_;
    unsigned short* WrT = A2  + (size_t)M_ * ALL_;
    unsigned short* WwT = WrT + (size_t)TWOALL_ * PD_;

    convert_f32_bf16<<<dim3((M_ * PD_ / 4 + 255) / 256), 256, 0, stream>>>(
        x, xbf, M_ * PD_ / 4);

    dim3 tb(32, 8);
    transpose_f32_bf16<<<dim3(TWOALL_ / 32, PD_ / 32), tb, 0, stream>>>(W_r, WrT, PD_, TWOALL_);
    transpose_f32_bf16<<<dim3(ALL_ / 32, PD_ / 32), tb, 0, stream>>>(W_w, WwT, PD_, ALL_);

    // GEMM1: P(bf16) = x @ W_r + b_r  (M=16384, N=2048, K=1024), grid 8x128
    gemm_bf16<1><<<dim3((TWOALL_ / BN) * (M_ / BM)), 256, 0, stream>>>(
        xbf, WrT, b_r, P, M_, TWOALL_, PD_, 3);

    middle_kernel<<<dim3((B_ * N_ * S_) / 256), 256, 0, stream>>>(P, A2);

    // GEMM2: out(f32) = A2 @ W_w + b_w  (M=16384, N=1024, K=1024), grid 4x128
    gemm_bf16<0><<<dim3((ALL_ / BN) * (M_ / BM)), 256, 0, stream>>>(
        A2, WwT, b_w, out, M_, ALL_, PD_, 2);
}